// Round 1
// baseline (1565.205 us; speedup 1.0000x reference)
//
#include <hip/hip_runtime.h>

// EquivariantProductBasisBlock (MACE symmetric contraction, corr=3) + o3.Linear
// N=10000 nodes, C=128 channels, L=9 (lmax=2), E=5 elements, fp32 throughout.
//
// Strategy:
//  - node_attrs is one-hot -> per-node element id e(b). Pre-contract U (x) w
//    into per-(e,c) polynomial coefficient tables T3/T2/T1 (3276 floats each).
//  - Counting-sort node indices by element so each block is (c, e, node-chunk):
//    its coefficient table (13 KB) sits in LDS, reads are wave-uniform
//    (broadcast, no bank conflicts). 4 nodes/thread keeps VALU dominant.
//  - Contraction output written as tmp[dd][c][p] (p = sorted position) ->
//    coalesced stores. Linear kernel does the per-l channel mixing GEMMs,
//    adds sc, and un-permutes (p -> n) on the final coalesced-ish write.

#define CCH 128
#define LDIM 9
#define NE 5
#define TSTRIDE 3280          // 3276 coeffs padded to a float4 multiple
#define T2_OFF 2916
#define T1_OFF 3240
#define NPT 4                 // nodes per thread in contraction kernel
#define BLK 256

// ---------------------------------------------------------------- sort nodes
__global__ __launch_bounds__(BLK) void sort_kernel(
    const float* __restrict__ attrs, int N,
    int* __restrict__ order, int* __restrict__ elem, int* __restrict__ offs) {
  __shared__ int cnt[NE];
  __shared__ int cur[NE];
  int tid = threadIdx.x;
  if (tid < NE) cnt[tid] = 0;
  __syncthreads();
  for (int n = tid; n < N; n += BLK) {
    const float* a = attrs + n * NE;
    int e = 0;
#pragma unroll
    for (int j = 1; j < NE; ++j)
      if (a[j] > 0.5f) e = j;
    elem[n] = e;
    atomicAdd(&cnt[e], 1);
  }
  __syncthreads();
  if (tid == 0) {
    int acc = 0;
    for (int k = 0; k < NE; ++k) { offs[k] = acc; cur[k] = acc; acc += cnt[k]; }
    offs[NE] = acc;
  }
  __syncthreads();
  for (int n = tid; n < N; n += BLK) {
    int e = elem[n];
    int p = atomicAdd(&cur[e], 1);
    order[p] = n;
  }
}

// ------------------------------------------------- build U (x) w coefficient tables
__global__ __launch_bounds__(BLK) void table_kernel(
    const float* __restrict__ U3_0, const float* __restrict__ U2_0,
    const float* __restrict__ U1_0, const float* __restrict__ U3_1,
    const float* __restrict__ U2_1, const float* __restrict__ U1_1,
    const float* __restrict__ w3_0, const float* __restrict__ w2_0,
    const float* __restrict__ w1_0, const float* __restrict__ w3_1,
    const float* __restrict__ w2_1, const float* __restrict__ w1_1,
    float* __restrict__ table) {
  int b = blockIdx.x;              // e*CCH + c
  int e = b / CCH, c = b % CCH;
  float* T = table + (size_t)b * TSTRIDE;
  for (int idx = threadIdx.x; idx < TSTRIDE; idx += BLK) {
    float acc = 0.f;
    if (idx < 2916) {              // T3[dd][u][v][w], dd=0 irrep0, 1..3 irrep1
      int dd = idx / 729, rem = idx % 729;   // rem = u*81+v*9+w
      if (dd == 0) {
        for (int k = 0; k < 10; ++k)
          acc += U3_0[rem * 10 + k] * w3_0[(e * 10 + k) * CCH + c];
      } else {
        int d = dd - 1;
        for (int k = 0; k < 12; ++k)
          acc += U3_1[(d * 729 + rem) * 12 + k] * w3_1[(e * 12 + k) * CCH + c];
      }
    } else if (idx < 3240) {       // T2[dd][u][v]
      int i2 = idx - 2916;
      int dd = i2 / 81, rem = i2 % 81;
      if (dd == 0) {
        for (int k = 0; k < 3; ++k)
          acc += U2_0[rem * 3 + k] * w2_0[(e * 3 + k) * CCH + c];
      } else {
        int d = dd - 1;
        for (int k = 0; k < 4; ++k)
          acc += U2_1[(d * 81 + rem) * 4 + k] * w2_1[(e * 4 + k) * CCH + c];
      }
    } else if (idx < 3276) {       // T1[dd][u]
      int i1 = idx - 3240;
      int dd = i1 / 9, u = i1 % 9;
      if (dd == 0) acc = U1_0[u] * w1_0[e * CCH + c];
      else         acc = U1_1[(dd - 1) * 9 + u] * w1_1[e * CCH + c];
    }
    T[idx] = acc;
  }
}

// ------------------------------------------------------- symmetric contraction
__global__ __launch_bounds__(BLK) void contract_kernel(
    const float* __restrict__ feats, const float* __restrict__ table,
    const int* __restrict__ order, const int* __restrict__ offs,
    float* __restrict__ tmp, int NPAD) {
  const int c = blockIdx.y, e = blockIdx.z;
  const int start = offs[e], end = offs[e + 1];
  const int base = start + blockIdx.x * (BLK * NPT);
  if (base >= end) return;                      // block-uniform early exit

  __shared__ float T[TSTRIDE];
  {
    const float4* src = (const float4*)(table + (size_t)(e * CCH + c) * TSTRIDE);
    float4* dst = (float4*)T;
    for (int i = threadIdx.x; i < TSTRIDE / 4; i += BLK) dst[i] = src[i];
  }
  __syncthreads();

  const int tid = threadIdx.x;
  float x[NPT][LDIM];
  int pp[NPT];
  int valid[NPT];
#pragma unroll
  for (int i = 0; i < NPT; ++i) {
    int p = base + i * BLK + tid;
    valid[i] = (p < end);
    pp[i] = valid[i] ? p : 0;
#pragma unroll
    for (int w = 0; w < LDIM; ++w) x[i][w] = 0.f;
    if (valid[i]) {
      int n = order[p];
      const float* xp = feats + ((size_t)n * CCH + c) * LDIM;
#pragma unroll
      for (int w = 0; w < LDIM; ++w) x[i][w] = xp[w];
    }
  }

  for (int dd = 0; dd < 4; ++dd) {
    const float* T3 = T + dd * 729;
    const float* T2 = T + T2_OFF + dd * 81;
    const float* T1 = T + T1_OFF + dd * 9;
    float accd[NPT];
#pragma unroll
    for (int i = 0; i < NPT; ++i) accd[i] = 0.f;
    for (int u = 0; u < 9; ++u) {
      float t1 = T1[u];
      float accu[NPT];
#pragma unroll
      for (int i = 0; i < NPT; ++i) accu[i] = t1;
#pragma unroll
      for (int v = 0; v < 9; ++v) {
        float t2 = T2[u * 9 + v];
        float accv[NPT];
#pragma unroll
        for (int i = 0; i < NPT; ++i) accv[i] = t2;
#pragma unroll
        for (int w = 0; w < 9; ++w) {
          float t3 = T3[(u * 9 + v) * 9 + w];
#pragma unroll
          for (int i = 0; i < NPT; ++i) accv[i] = fmaf(x[i][w], t3, accv[i]);
        }
#pragma unroll
        for (int i = 0; i < NPT; ++i) accu[i] = fmaf(accv[i], x[i][v], accu[i]);
      }
#pragma unroll
      for (int i = 0; i < NPT; ++i) accd[i] = fmaf(accu[i], x[i][u], accd[i]);
    }
    float* o = tmp + (size_t)(dd * CCH + c) * NPAD;
#pragma unroll
    for (int i = 0; i < NPT; ++i)
      if (valid[i]) o[pp[i]] = accd[i];         // consecutive p -> coalesced
  }
}

// ------------------------------------------------------ o3.Linear + residual
__global__ __launch_bounds__(BLK) void linear_kernel(
    const float* __restrict__ tmp, const float* __restrict__ W0,
    const float* __restrict__ W1, const float* __restrict__ sc,
    const int* __restrict__ order, float* __restrict__ out, int N, int NPAD) {
  const int dd = blockIdx.y;                    // 0..3
  const int co = threadIdx.x & (CCH - 1);
  const int half = threadIdx.x >> 7;            // 0/1
  const int PT = 8;
  const int p0 = blockIdx.x * (PT * 2) + half * PT;
  if (p0 >= N) return;
  const float* W = (dd == 0) ? W0 : W1;
  const float* A = tmp + (size_t)(dd * CCH) * NPAD + p0;
  float acc[PT];
#pragma unroll
  for (int j = 0; j < PT; ++j) acc[j] = 0.f;
  for (int ci = 0; ci < CCH; ++ci) {
    float wv = W[ci * CCH + co];                // coalesced across lanes
    const float4* ap4 = (const float4*)(A + (size_t)ci * NPAD);
    float4 a0 = ap4[0], a1 = ap4[1];            // wave-uniform -> broadcast
    acc[0] = fmaf(a0.x, wv, acc[0]);
    acc[1] = fmaf(a0.y, wv, acc[1]);
    acc[2] = fmaf(a0.z, wv, acc[2]);
    acc[3] = fmaf(a0.w, wv, acc[3]);
    acc[4] = fmaf(a1.x, wv, acc[4]);
    acc[5] = fmaf(a1.y, wv, acc[5]);
    acc[6] = fmaf(a1.z, wv, acc[6]);
    acc[7] = fmaf(a1.w, wv, acc[7]);
  }
  const float s = 0.08838834764831843f;         // 1/sqrt(128)
#pragma unroll
  for (int j = 0; j < PT; ++j) {
    int p = p0 + j;
    if (p < N) {
      int n = order[p];
      int off = (dd == 0) ? co : (CCH + co * 3 + (dd - 1));
      size_t oi = (size_t)n * 512 + off;
      out[oi] = acc[j] * s + sc[oi];
    }
  }
}

// -------------------------------------------------------------------- launch
extern "C" void kernel_launch(void* const* d_in, const int* in_sizes, int n_in,
                              void* d_out, int out_size, void* d_ws, size_t ws_size,
                              hipStream_t stream) {
  const float* feats = (const float*)d_in[0];
  const float* attrs = (const float*)d_in[1];
  const float* sc    = (const float*)d_in[2];
  const float* U3_0  = (const float*)d_in[3];
  const float* U2_0  = (const float*)d_in[4];
  const float* U1_0  = (const float*)d_in[5];
  const float* w3_0  = (const float*)d_in[6];
  const float* w2_0  = (const float*)d_in[7];
  const float* w1_0  = (const float*)d_in[8];
  const float* U3_1  = (const float*)d_in[9];
  const float* U2_1  = (const float*)d_in[10];
  const float* U1_1  = (const float*)d_in[11];
  const float* w3_1  = (const float*)d_in[12];
  const float* w2_1  = (const float*)d_in[13];
  const float* w1_1  = (const float*)d_in[14];
  const float* W0    = (const float*)d_in[15];
  const float* W1    = (const float*)d_in[16];

  const int N = in_sizes[0] / (CCH * LDIM);     // 10000
  const int NPAD = ((N + 15) & ~15) + 16;

  // workspace layout (floats): tables | tmp[4*C][NPAD] | order[N] elem[N] offs[8]
  float* table = (float*)d_ws;
  float* tmp   = table + (size_t)NE * CCH * TSTRIDE;
  int*   order = (int*)(tmp + (size_t)4 * CCH * NPAD);
  int*   elem  = order + N;
  int*   offs  = elem + N;
  float* out   = (float*)d_out;

  sort_kernel<<<dim3(1), dim3(BLK), 0, stream>>>(attrs, N, order, elem, offs);
  table_kernel<<<dim3(NE * CCH), dim3(BLK), 0, stream>>>(
      U3_0, U2_0, U1_0, U3_1, U2_1, U1_1,
      w3_0, w2_0, w1_0, w3_1, w2_1, w1_1, table);

  const int chunks = (N + BLK * NPT - 1) / (BLK * NPT);
  contract_kernel<<<dim3(chunks, CCH, NE), dim3(BLK), 0, stream>>>(
      feats, table, order, offs, tmp, NPAD);

  linear_kernel<<<dim3((N + 15) / 16, 4), dim3(BLK), 0, stream>>>(
      tmp, W0, W1, sc, order, out, N, NPAD);
}

// Round 2
// 524.095 us; speedup vs baseline: 2.9865x; 2.9865x over previous
//
#include <hip/hip_runtime.h>

// EquivariantProductBasisBlock (MACE symmetric contraction, corr=3) + o3.Linear
// N=10000 nodes, C=128 channels, L=9 (lmax=2), E=5 elements, fp32 throughout.
//
// R2 changes vs R1: contract_kernel was spill-bound (VGPR=256, 2 GB scratch
// writes). Now: __launch_bounds__(256,4) caps VGPR at 128; dd/u/v loops pinned
// to unroll(1) so the compiler can't blow the register budget; T3 rows padded
// to 12 floats (16B-aligned) so per-v LDS reads are 2x ds_read_b128 + b32.

#define CCH 128
#define LDIM 9
#define NE 5
// table layout per (e,c): T3[dd][81 rows][12 padded] | T2[dd][81] | T1[dd][9]
#define T3ROW 12
#define T2_OFF 3888           // 4*81*12
#define T1_OFF 4212           // + 4*81
#define TSTRIDE 4248          // + 4*9  (multiple of 4)
#define NPT 4                 // nodes per thread in contraction kernel
#define BLK 256

// ---------------------------------------------------------------- sort nodes
__global__ __launch_bounds__(BLK) void sort_kernel(
    const float* __restrict__ attrs, int N,
    int* __restrict__ order, int* __restrict__ elem, int* __restrict__ offs) {
  __shared__ int cnt[NE];
  __shared__ int cur[NE];
  int tid = threadIdx.x;
  if (tid < NE) cnt[tid] = 0;
  __syncthreads();
  for (int n = tid; n < N; n += BLK) {
    const float* a = attrs + n * NE;
    int e = 0;
#pragma unroll
    for (int j = 1; j < NE; ++j)
      if (a[j] > 0.5f) e = j;
    elem[n] = e;
    atomicAdd(&cnt[e], 1);
  }
  __syncthreads();
  if (tid == 0) {
    int acc = 0;
    for (int k = 0; k < NE; ++k) { offs[k] = acc; cur[k] = acc; acc += cnt[k]; }
    offs[NE] = acc;
  }
  __syncthreads();
  for (int n = tid; n < N; n += BLK) {
    int e = elem[n];
    int p = atomicAdd(&cur[e], 1);
    order[p] = n;
  }
}

// ------------------------------------------------- build U (x) w coefficient tables
__global__ __launch_bounds__(BLK) void table_kernel(
    const float* __restrict__ U3_0, const float* __restrict__ U2_0,
    const float* __restrict__ U1_0, const float* __restrict__ U3_1,
    const float* __restrict__ U2_1, const float* __restrict__ U1_1,
    const float* __restrict__ w3_0, const float* __restrict__ w2_0,
    const float* __restrict__ w1_0, const float* __restrict__ w3_1,
    const float* __restrict__ w2_1, const float* __restrict__ w1_1,
    float* __restrict__ table) {
  int b = blockIdx.x;              // e*CCH + c
  int e = b / CCH, c = b % CCH;
  float* T = table + (size_t)b * TSTRIDE;
  for (int idx = threadIdx.x; idx < TSTRIDE; idx += BLK) {
    float acc = 0.f;
    if (idx < T2_OFF) {            // T3[dd][u*9+v][w(pad 12)], dd=0 irrep0
      int dd = idx / 972, rem = idx % 972;
      int uv = rem / T3ROW, w = rem % T3ROW;
      if (w < 9) {
        int r = uv * 9 + w;        // u*81+v*9+w
        if (dd == 0) {
          for (int k = 0; k < 10; ++k)
            acc += U3_0[r * 10 + k] * w3_0[(e * 10 + k) * CCH + c];
        } else {
          int d = dd - 1;
          for (int k = 0; k < 12; ++k)
            acc += U3_1[(d * 729 + r) * 12 + k] * w3_1[(e * 12 + k) * CCH + c];
        }
      }
    } else if (idx < T1_OFF) {     // T2[dd][u*9+v]
      int i2 = idx - T2_OFF;
      int dd = i2 / 81, rem = i2 % 81;
      if (dd == 0) {
        for (int k = 0; k < 3; ++k)
          acc += U2_0[rem * 3 + k] * w2_0[(e * 3 + k) * CCH + c];
      } else {
        int d = dd - 1;
        for (int k = 0; k < 4; ++k)
          acc += U2_1[(d * 81 + rem) * 4 + k] * w2_1[(e * 4 + k) * CCH + c];
      }
    } else if (idx < TSTRIDE) {    // T1[dd][u]
      int i1 = idx - T1_OFF;
      int dd = i1 / 9, u = i1 % 9;
      if (dd == 0) acc = U1_0[u] * w1_0[e * CCH + c];
      else         acc = U1_1[(dd - 1) * 9 + u] * w1_1[e * CCH + c];
    }
    T[idx] = acc;
  }
}

// ------------------------------------------------------- symmetric contraction
__global__ __launch_bounds__(BLK, 4) void contract_kernel(
    const float* __restrict__ feats, const float* __restrict__ table,
    const int* __restrict__ order, const int* __restrict__ offs,
    float* __restrict__ tmp, int NPAD) {
  const int c = blockIdx.y, e = blockIdx.z;
  const int start = offs[e], end = offs[e + 1];
  const int base = start + blockIdx.x * (BLK * NPT);
  if (base >= end) return;                      // block-uniform early exit

  __shared__ float T[TSTRIDE];
  {
    const float4* src = (const float4*)(table + (size_t)(e * CCH + c) * TSTRIDE);
    float4* dst = (float4*)T;
    for (int i = threadIdx.x; i < TSTRIDE / 4; i += BLK) dst[i] = src[i];
  }
  __syncthreads();

  const int tid = threadIdx.x;
  float x[NPT][LDIM];
  int pp[NPT];
  int valid[NPT];
#pragma unroll
  for (int i = 0; i < NPT; ++i) {
    int p = base + i * BLK + tid;
    valid[i] = (p < end);
    pp[i] = valid[i] ? p : 0;
#pragma unroll
    for (int w = 0; w < LDIM; ++w) x[i][w] = 0.f;
    if (valid[i]) {
      int n = order[p];
      const float* xp = feats + ((size_t)n * CCH + c) * LDIM;
#pragma unroll
      for (int w = 0; w < LDIM; ++w) x[i][w] = xp[w];
    }
  }

#pragma unroll 1
  for (int dd = 0; dd < 4; ++dd) {
    const float* T3 = T + dd * 972;
    const float* T2 = T + T2_OFF + dd * 81;
    const float* T1 = T + T1_OFF + dd * 9;
    float accd[NPT];
#pragma unroll
    for (int i = 0; i < NPT; ++i) accd[i] = 0.f;
#pragma unroll 1
    for (int u = 0; u < 9; ++u) {
      float t1 = T1[u];
      float accu[NPT];
#pragma unroll
      for (int i = 0; i < NPT; ++i) accu[i] = t1;
#pragma unroll 1
      for (int v = 0; v < 9; ++v) {
        float t2 = T2[u * 9 + v];
        const float4* row = (const float4*)(T3 + (u * 9 + v) * T3ROW);
        float4 r0 = row[0];
        float4 r1 = row[1];
        float t38 = T3[(u * 9 + v) * T3ROW + 8];
        float accv[NPT];
#pragma unroll
        for (int i = 0; i < NPT; ++i) {
          float a = t2;
          a = fmaf(x[i][0], r0.x, a);
          a = fmaf(x[i][1], r0.y, a);
          a = fmaf(x[i][2], r0.z, a);
          a = fmaf(x[i][3], r0.w, a);
          a = fmaf(x[i][4], r1.x, a);
          a = fmaf(x[i][5], r1.y, a);
          a = fmaf(x[i][6], r1.z, a);
          a = fmaf(x[i][7], r1.w, a);
          a = fmaf(x[i][8], t38, a);
          accv[i] = a;
        }
#pragma unroll
        for (int i = 0; i < NPT; ++i) accu[i] = fmaf(accv[i], x[i][v], accu[i]);
      }
#pragma unroll
      for (int i = 0; i < NPT; ++i) accd[i] = fmaf(accu[i], x[i][u], accd[i]);
    }
    float* o = tmp + (size_t)(dd * CCH + c) * NPAD;
#pragma unroll
    for (int i = 0; i < NPT; ++i)
      if (valid[i]) o[pp[i]] = accd[i];         // consecutive p -> coalesced
  }
}

// ------------------------------------------------------ o3.Linear + residual
__global__ __launch_bounds__(BLK) void linear_kernel(
    const float* __restrict__ tmp, const float* __restrict__ W0,
    const float* __restrict__ W1, const float* __restrict__ sc,
    const int* __restrict__ order, float* __restrict__ out, int N, int NPAD) {
  const int dd = blockIdx.y;                    // 0..3
  const int co = threadIdx.x & (CCH - 1);
  const int half = threadIdx.x >> 7;            // 0/1
  const int PT = 8;
  const int p0 = blockIdx.x * (PT * 2) + half * PT;
  if (p0 >= N) return;
  const float* W = (dd == 0) ? W0 : W1;
  const float* A = tmp + (size_t)(dd * CCH) * NPAD + p0;
  float acc[PT];
#pragma unroll
  for (int j = 0; j < PT; ++j) acc[j] = 0.f;
  for (int ci = 0; ci < CCH; ++ci) {
    float wv = W[ci * CCH + co];                // coalesced across lanes
    const float4* ap4 = (const float4*)(A + (size_t)ci * NPAD);
    float4 a0 = ap4[0], a1 = ap4[1];            // wave-uniform -> broadcast
    acc[0] = fmaf(a0.x, wv, acc[0]);
    acc[1] = fmaf(a0.y, wv, acc[1]);
    acc[2] = fmaf(a0.z, wv, acc[2]);
    acc[3] = fmaf(a0.w, wv, acc[3]);
    acc[4] = fmaf(a1.x, wv, acc[4]);
    acc[5] = fmaf(a1.y, wv, acc[5]);
    acc[6] = fmaf(a1.z, wv, acc[6]);
    acc[7] = fmaf(a1.w, wv, acc[7]);
  }
  const float s = 0.08838834764831843f;         // 1/sqrt(128)
#pragma unroll
  for (int j = 0; j < PT; ++j) {
    int p = p0 + j;
    if (p < N) {
      int n = order[p];
      int off = (dd == 0) ? co : (CCH + co * 3 + (dd - 1));
      size_t oi = (size_t)n * 512 + off;
      out[oi] = acc[j] * s + sc[oi];
    }
  }
}

// -------------------------------------------------------------------- launch
extern "C" void kernel_launch(void* const* d_in, const int* in_sizes, int n_in,
                              void* d_out, int out_size, void* d_ws, size_t ws_size,
                              hipStream_t stream) {
  const float* feats = (const float*)d_in[0];
  const float* attrs = (const float*)d_in[1];
  const float* sc    = (const float*)d_in[2];
  const float* U3_0  = (const float*)d_in[3];
  const float* U2_0  = (const float*)d_in[4];
  const float* U1_0  = (const float*)d_in[5];
  const float* w3_0  = (const float*)d_in[6];
  const float* w2_0  = (const float*)d_in[7];
  const float* w1_0  = (const float*)d_in[8];
  const float* U3_1  = (const float*)d_in[9];
  const float* U2_1  = (const float*)d_in[10];
  const float* U1_1  = (const float*)d_in[11];
  const float* w3_1  = (const float*)d_in[12];
  const float* w2_1  = (const float*)d_in[13];
  const float* w1_1  = (const float*)d_in[14];
  const float* W0    = (const float*)d_in[15];
  const float* W1    = (const float*)d_in[16];

  const int N = in_sizes[0] / (CCH * LDIM);     // 10000
  const int NPAD = ((N + 15) & ~15) + 16;

  // workspace layout (floats): tables | tmp[4*C][NPAD] | order[N] elem[N] offs[8]
  float* table = (float*)d_ws;
  float* tmp   = table + (size_t)NE * CCH * TSTRIDE;
  int*   order = (int*)(tmp + (size_t)4 * CCH * NPAD);
  int*   elem  = order + N;
  int*   offs  = elem + N;
  float* out   = (float*)d_out;

  sort_kernel<<<dim3(1), dim3(BLK), 0, stream>>>(attrs, N, order, elem, offs);
  table_kernel<<<dim3(NE * CCH), dim3(BLK), 0, stream>>>(
      U3_0, U2_0, U1_0, U3_1, U2_1, U1_1,
      w3_0, w2_0, w1_0, w3_1, w2_1, w1_1, table);

  const int chunks = (N + BLK * NPT - 1) / (BLK * NPT);
  contract_kernel<<<dim3(chunks, CCH, NE), dim3(BLK), 0, stream>>>(
      feats, table, order, offs, tmp, NPAD);

  linear_kernel<<<dim3((N + 15) / 16, 4), dim3(BLK), 0, stream>>>(
      tmp, W0, W1, sc, order, out, N, NPAD);
}